// Round 15
// baseline (393.038 us; speedup 1.0000x reference)
//
#include <hip/hip_runtime.h>
#include <math.h>

#define HW 2304
#define NB 8
#define CH 256
#define QC 512
#define NH 4
#define DK 32
#define DV 64
#define EPS 1e-3f

typedef __bf16 bf16;
typedef bf16 bf16x8 __attribute__((ext_vector_type(8)));
typedef bf16 bf16x4 __attribute__((ext_vector_type(4)));
typedef float f32x4 __attribute__((ext_vector_type(4)));

// scale * log2(e), folded into Q weights so softmax uses exp2 directly
#define QSC (0.17677669529663687f * 1.4426950408889634f)

// ---------------- wprep: fold BN into bf16 weights ----------------
// grid 512 x 256
__global__ __launch_bounds__(256) void wprep(
    const float* __restrict__ qkv_w, const float* __restrict__ qkv_g,
    const float* __restrict__ qkv_b, const float* __restrict__ qkv_m,
    const float* __restrict__ qkv_v,
    const float* __restrict__ c1_w, const float* __restrict__ c1_g,
    const float* __restrict__ c1_b, const float* __restrict__ c1_m,
    const float* __restrict__ c1_v,
    const float* __restrict__ c2_w, const float* __restrict__ c2_g,
    const float* __restrict__ c2_b, const float* __restrict__ c2_m,
    const float* __restrict__ c2_v,
    bf16* __restrict__ Wq, float* __restrict__ bq,
    bf16* __restrict__ W2, float* __restrict__ b2,
    float* __restrict__ W1)
{
  const int tid = blockIdx.x * 256 + threadIdx.x;  // 0..131071
  {
    const int co = tid >> 8;
    const float s = qkv_g[co] / sqrtf(qkv_v[co] + EPS);
    const float f = ((co & 127) < DK) ? QSC : 1.f;
    Wq[tid] = (bf16)(qkv_w[tid] * s * f);
  }
  if (tid < 65536) {
    const int co = tid >> 8;
    const float s = c2_g[co] / sqrtf(c2_v[co] + EPS);
    W2[tid] = (bf16)(c2_w[tid] * s);
  }
  if (tid < 2560) {
    const int c = tid / 10, k = tid - c * 10;
    const float s = c1_g[c] / sqrtf(c1_v[c] + EPS);
    float v;
    if (k < 9) v = c1_w[c * 9 + k] * s;
    else       v = c1_b[c] - c1_m[c] * s;
    W1[tid] = v;
  }
  if (tid < QC) {
    const float s = qkv_g[tid] / sqrtf(qkv_v[tid] + EPS);
    const float f = ((tid & 127) < DK) ? QSC : 1.f;
    bq[tid] = (qkv_b[tid] - qkv_m[tid] * s) * f;
  }
  if (tid < CH) {
    const float s = c2_g[tid] / sqrtf(c2_v[tid] + EPS);
    b2[tid] = c2_b[tid] - c2_m[tid] * s;
  }
}

// ---------------- xprep: x fp32 [b][ci][p] -> Xt bf16 [b][p][ci] ----------------
// grid (36, 4, 8) x 256; tile 64ci x 64p via padded LDS
__global__ __launch_bounds__(256) void xprep(
    const float* __restrict__ x, bf16* __restrict__ Xt)
{
  __shared__ float T[64][65];
  const int t = threadIdx.x;
  const int p0 = blockIdx.x * 64;
  const int ci0 = blockIdx.y * 64;
  const int b = blockIdx.z;
  #pragma unroll
  for (int r = 0; r < 4; ++r) {         // 1024 float4s = 64ci x 16 chunks
    const int e = t + 256 * r;
    const int ci = e >> 4, p4 = (e & 15) * 4;
    const float4 v = *reinterpret_cast<const float4*>(
        x + ((size_t)(b * CH + ci0 + ci)) * HW + p0 + p4);
    T[ci][p4 + 0] = v.x; T[ci][p4 + 1] = v.y;
    T[ci][p4 + 2] = v.z; T[ci][p4 + 3] = v.w;
  }
  __syncthreads();
  #pragma unroll
  for (int r = 0; r < 2; ++r) {
    const int e = t + 256 * r;          // 0..511 8-chunks
    const int p = e >> 3, c8 = (e & 7) * 8;
    bf16x8 pk;
    #pragma unroll
    for (int j = 0; j < 8; ++j) pk[j] = (bf16)T[c8 + j][p];
    *reinterpret_cast<bf16x8*>(Xt + ((size_t)b * HW + p0 + p) * CH + ci0 + c8) = pk;
  }
}

// ---------------- qkv_gemm: [512 co] x [256 ci] x [64 p] tiles ----------------
// Emits Qb/Kb token-major [bh][tok][32] (scale+log2e folded in Wq), Vb [bh][d][tok].
// grid (36, 8, 8) x 256 (4 waves, no barriers, no LDS)
__global__ __launch_bounds__(256) void qkv_gemm(
    const bf16* __restrict__ Xt, const bf16* __restrict__ Wq,
    const float* __restrict__ bq,
    bf16* __restrict__ Qb, bf16* __restrict__ Kb, bf16* __restrict__ Vb)
{
  const int t = threadIdx.x;
  const int wv = t >> 6, l = t & 63, li = l & 15, g = l >> 4;
  const int cow = blockIdx.y * 64 + wv * 16;
  const int p0 = blockIdx.x * 64;
  const int b = blockIdx.z;
  const bf16* Bb = Xt + ((size_t)b * HW + p0) * CH;
  const bf16* Ab = Wq + (size_t)(cow + li) * CH + g * 8;
  f32x4 acc[4] = {{0.f,0.f,0.f,0.f},{0.f,0.f,0.f,0.f},
                  {0.f,0.f,0.f,0.f},{0.f,0.f,0.f,0.f}};
  #pragma unroll
  for (int k0 = 0; k0 < CH; k0 += 32) {
    const bf16x8 af = *reinterpret_cast<const bf16x8*>(Ab + k0);
    #pragma unroll
    for (int pt = 0; pt < 4; ++pt) {
      const bf16x8 bfr = *reinterpret_cast<const bf16x8*>(
          Bb + (size_t)(pt * 16 + li) * CH + k0 + g * 8);
      acc[pt] = __builtin_amdgcn_mfma_f32_16x16x32_bf16(af, bfr, acc[pt], 0, 0, 0);
    }
  }
  // lane holds D[co = cow + g*4 + r][p = p0 + pt*16 + li]
  const float4 bv = *reinterpret_cast<const float4*>(bq + cow + g * 4);
  const int r0 = cow & 127;
  const int h = cow >> 7;
  const int bh = b * NH + h;
  if (r0 < 2 * DK) {                    // Q or K: token-major
    bf16* dst = (r0 < DK) ? Qb : Kb;
    const int kk0 = (r0 & 31) + g * 4;
    #pragma unroll
    for (int pt = 0; pt < 4; ++pt) {
      bf16x4 pk;
      pk[0] = (bf16)(acc[pt][0] + bv.x); pk[1] = (bf16)(acc[pt][1] + bv.y);
      pk[2] = (bf16)(acc[pt][2] + bv.z); pk[3] = (bf16)(acc[pt][3] + bv.w);
      *reinterpret_cast<bf16x4*>(
          dst + ((size_t)bh * HW + p0 + pt * 16 + li) * DK + kk0) = pk;
    }
  } else {                              // V: channel-major
    const int d0 = (r0 - 2 * DK) + g * 4;
    #pragma unroll
    for (int pt = 0; pt < 4; ++pt) {
      const int p = p0 + pt * 16 + li;
      Vb[((size_t)bh * DV + d0 + 0) * HW + p] = (bf16)(acc[pt][0] + bv.x);
      Vb[((size_t)bh * DV + d0 + 1) * HW + p] = (bf16)(acc[pt][1] + bv.y);
      Vb[((size_t)bh * DV + d0 + 2) * HW + p] = (bf16)(acc[pt][2] + bv.z);
      Vb[((size_t)bh * DV + d0 + 3) * HW + p] = (bf16)(acc[pt][3] + bv.w);
    }
  }
}

// ---------------- dwc: Dw = BN(dwconv3x3(V)) in channel-major bf16 ----------------
// Vb [bh*64+d][tok] -> Dw [bh*64+d][tok], bias included. Fully coalesced.
// grid 2304 x 256
__global__ __launch_bounds__(256) void dwc(
    const bf16* __restrict__ Vb, const float* __restrict__ W1,
    bf16* __restrict__ Dw)
{
  const int gid = blockIdx.x * 256 + threadIdx.x;  // 0..589823
  const int c = gid / 288;                          // bh*64+d
  const int ck = gid - c * 288;
  const int p0 = ck * 8;
  const int y = p0 / 48, x0 = p0 - y * 48;          // x0 in {0,8,...,40}
  const float* wc = W1 + (c & 255) * 10;
  float w[9];
  #pragma unroll
  for (int k = 0; k < 9; ++k) w[k] = wc[k];
  float o[8];
  #pragma unroll
  for (int j = 0; j < 8; ++j) o[j] = wc[9];
  const bf16* vch = Vb + (size_t)c * HW;
  #pragma unroll
  for (int ky = 0; ky < 3; ++ky) {
    const int yy = y + ky - 1;
    if (yy < 0 || yy >= 48) continue;
    const bf16* row = vch + yy * 48 + x0;
    const bf16x8 mid = *reinterpret_cast<const bf16x8*>(row);
    float v[10];
    v[0] = (x0 > 0)  ? (float)row[-1] : 0.f;
    #pragma unroll
    for (int j = 0; j < 8; ++j) v[j + 1] = (float)mid[j];
    v[9] = (x0 < 40) ? (float)row[8]  : 0.f;
    #pragma unroll
    for (int kx = 0; kx < 3; ++kx) {
      const float wk = w[ky * 3 + kx];
      #pragma unroll
      for (int j = 0; j < 8; ++j) o[j] = fmaf(wk, v[j + kx], o[j]);
    }
  }
  bf16x8 pk;
  #pragma unroll
  for (int j = 0; j < 8; ++j) pk[j] = (bf16)o[j];
  *reinterpret_cast<bf16x8*>(Dw + (size_t)c * HW + p0) = pk;
}

// ---------------- flash_attn: j-split x2, pinned K+V reg prefetch ----------------
// 512 threads = 8 waves; wave = (i-tile it, j-half jh). The vc[16]/kc[8] prefetch
// is pinned BEFORE the softmax VALU phase by sched_barrier(0): the loads' results
// are live across the fence, forcing the allocator (budget 256 via
// __launch_bounds__(512,2)) to materialize them instead of sinking the loads to
// their use sites (R12/R14: VGPR=64, loads serialized, MfmaUtil 6%).
// grid (36, 32) x 512
__global__ __launch_bounds__(512, 2) void flash_attn(
    const bf16* __restrict__ Qb, const bf16* __restrict__ Kb,
    const bf16* __restrict__ Vb, const bf16* __restrict__ Dw,
    bf16* __restrict__ F)
{
  __shared__ bf16 Plds[8][16][136];   // 34816 B; combine buffer overlays after barrier
  const int t = threadIdx.x;
  const int wv = t >> 6;
  const int l = t & 63;
  const int li = l & 15;
  const int gq = l >> 4;
  const int it = wv & 3, jh = wv >> 2;
  const int bh = blockIdx.y;
  const int b = bh >> 2, h = bh & 3;
  const int i0 = blockIdx.x * 64 + it * 16;

  const bf16x8 qf = *reinterpret_cast<const bf16x8*>(
      Qb + ((size_t)bh * HW + i0 + li) * DK + gq * 8);
  const bf16* Kbase = Kb + (size_t)bh * HW * DK;
  const bf16* Vbase = Vb + (size_t)bh * DV * HW;

  f32x4 acc[4] = {{0.f,0.f,0.f,0.f},{0.f,0.f,0.f,0.f},
                  {0.f,0.f,0.f,0.f},{0.f,0.f,0.f,0.f}};
  float m_run = -INFINITY, l_run = 0.f;

  const int jbeg = jh * (HW / 2);
  const int jend = jbeg + (HW / 2);    // 9 tiles of 128

  // prefetch K fragments for first tile
  bf16x8 kc[8];
  #pragma unroll
  for (int jt = 0; jt < 8; ++jt)
    kc[jt] = *reinterpret_cast<const bf16x8*>(
        Kbase + (size_t)(jbeg + jt * 16 + li) * DK + gq * 8);

  for (int j0 = jbeg; j0 < jend; j0 += 128) {
    f32x4 st[8];
    #pragma unroll
    for (int jt = 0; jt < 8; ++jt)
      st[jt] = __builtin_amdgcn_mfma_f32_16x16x32_bf16(
          kc[jt], qf, (f32x4){0.f,0.f,0.f,0.f}, 0, 0, 0);
    // issue current-tile V loads first (needed by PV: compiler can resume at
    // vmcnt(8) with kc still in flight), then next-tile K loads.
    bf16x8 vc[16];
    #pragma unroll
    for (int kt = 0; kt < 4; ++kt)
      #pragma unroll
      for (int dt = 0; dt < 4; ++dt)
        vc[kt * 4 + dt] = *reinterpret_cast<const bf16x8*>(
            Vbase + (size_t)(dt * 16 + li) * HW + j0 + kt * 32 + gq * 8);
    const int jn = (j0 + 128 < jend) ? (j0 + 128) : jbeg;
    #pragma unroll
    for (int jt = 0; jt < 8; ++jt)
      kc[jt] = *reinterpret_cast<const bf16x8*>(
          Kbase + (size_t)(jn + jt * 16 + li) * DK + gq * 8);
    // scheduling fence: nothing crosses. All 24 loads are now issued and in
    // flight across the entire softmax VALU phase below.
    __builtin_amdgcn_sched_barrier(0);

    float tm = -INFINITY;
    #pragma unroll
    for (int jt = 0; jt < 8; ++jt)
      #pragma unroll
      for (int r = 0; r < 4; ++r) tm = fmaxf(tm, st[jt][r]);
    tm = fmaxf(tm, __shfl_xor(tm, 16));
    tm = fmaxf(tm, __shfl_xor(tm, 32));
    const float mnew = fmaxf(m_run, tm);
    const float corr = __builtin_exp2f(m_run - mnew);
    m_run = mnew;
    l_run *= corr;
    #pragma unroll
    for (int dt = 0; dt < 4; ++dt)
      #pragma unroll
      for (int r = 0; r < 4; ++r) acc[dt][r] *= corr;
    float ps = 0.f;
    #pragma unroll
    for (int jt = 0; jt < 8; ++jt) {
      bf16x4 pb;
      #pragma unroll
      for (int r = 0; r < 4; ++r) {
        const float pv = __builtin_exp2f(st[jt][r] - mnew);
        ps += pv;
        pb[r] = (bf16)pv;
      }
      *reinterpret_cast<bf16x4*>(&Plds[wv][li][jt * 16 + gq * 4]) = pb;
    }
    ps += __shfl_xor(ps, 16);
    ps += __shfl_xor(ps, 32);
    l_run += ps;
    #pragma unroll
    for (int kt = 0; kt < 4; ++kt) {
      const bf16x8 pf = *reinterpret_cast<const bf16x8*>(
          &Plds[wv][li][kt * 32 + gq * 8]);
      #pragma unroll
      for (int dt = 0; dt < 4; ++dt)
        acc[dt] = __builtin_amdgcn_mfma_f32_16x16x32_bf16(
            vc[kt * 4 + dt], pf, acc[dt], 0, 0, 0);
    }
  }

  // ---- merge the two j-halves through LDS (overlays Plds) ----
  __syncthreads();                     // everyone done with Plds
  float* cacc = (float*)&Plds[0][0][0];        // [4][64][17]
  float* cml  = cacc + 4 * 64 * 17;            // [4][2][16]
  if (jh == 1) {
    float* dst = cacc + (wv - 4) * 64 * 17 + l * 17;
    #pragma unroll
    for (int dt = 0; dt < 4; ++dt)
      #pragma unroll
      for (int r = 0; r < 4; ++r) dst[dt * 4 + r] = acc[dt][r];
    if (gq == 0) {
      cml[(wv - 4) * 32 + li] = m_run;
      cml[(wv - 4) * 32 + 16 + li] = l_run;
    }
  }
  __syncthreads();
  if (jh == 0) {
    const float* src = cacc + wv * 64 * 17 + l * 17;
    const float mb = cml[wv * 32 + li];
    const float lb = cml[wv * 32 + 16 + li];
    const float m = fmaxf(m_run, mb);
    const float ca = __builtin_exp2f(m_run - m);
    const float cb = __builtin_exp2f(mb - m);
    const float linv = 1.f / (l_run * ca + lb * cb);
    const int i = i0 + li;
    const bf16* dwb = Dw + (size_t)bh * DV * HW + i;
    bf16* Fo = F + ((size_t)b * HW + i) * CH + h * DV;
    #pragma unroll
    for (int dt = 0; dt < 4; ++dt) {
      bf16x4 pk;
      #pragma unroll
      for (int r = 0; r < 4; ++r) {
        const int d = dt * 16 + gq * 4 + r;
        const float oa = (acc[dt][r] * ca + src[dt * 4 + r] * cb) * linv;
        pk[r] = (bf16)(oa + (float)dwb[(size_t)d * HW]);
      }
      *reinterpret_cast<bf16x4*>(Fo + dt * 16 + gq * 4) = pk;
    }
  }
}

// ---------------- c2_gemm: out = W2 . F + b2, fp32 out [b][co][p] ----------------
// grid (36, 4, 8) x 256
__global__ __launch_bounds__(256) void c2_gemm(
    const bf16* __restrict__ F, const bf16* __restrict__ W2,
    const float* __restrict__ b2, float* __restrict__ out)
{
  const int t = threadIdx.x;
  const int wv = t >> 6, l = t & 63, li = l & 15, g = l >> 4;
  const int cow = blockIdx.y * 64 + wv * 16;
  const int p0 = blockIdx.x * 64;
  const int b = blockIdx.z;
  const bf16* Bb = F + ((size_t)b * HW + p0) * CH;
  const bf16* Ab = W2 + (size_t)(cow + li) * CH + g * 8;
  f32x4 acc[4] = {{0.f,0.f,0.f,0.f},{0.f,0.f,0.f,0.f},
                  {0.f,0.f,0.f,0.f},{0.f,0.f,0.f,0.f}};
  #pragma unroll
  for (int k0 = 0; k0 < CH; k0 += 32) {
    const bf16x8 af = *reinterpret_cast<const bf16x8*>(Ab + k0);
    #pragma unroll
    for (int pt = 0; pt < 4; ++pt) {
      const bf16x8 bfr = *reinterpret_cast<const bf16x8*>(
          Bb + (size_t)(pt * 16 + li) * CH + k0 + g * 8);
      acc[pt] = __builtin_amdgcn_mfma_f32_16x16x32_bf16(af, bfr, acc[pt], 0, 0, 0);
    }
  }
  const float4 bv = *reinterpret_cast<const float4*>(b2 + cow + g * 4);
  #pragma unroll
  for (int pt = 0; pt < 4; ++pt) {
    const int p = p0 + pt * 16 + li;
    float* ob = out + ((size_t)b * CH + cow + g * 4) * HW + p;
    ob[0 * HW] = acc[pt][0] + bv.x;
    ob[1 * HW] = acc[pt][1] + bv.y;
    ob[2 * HW] = acc[pt][2] + bv.z;
    ob[3 * HW] = acc[pt][3] + bv.w;
  }
}

extern "C" void kernel_launch(void* const* d_in, const int* in_sizes, int n_in,
                              void* d_out, int out_size, void* d_ws, size_t ws_size,
                              hipStream_t stream)
{
  const float* x     = (const float*)d_in[0];
  const float* qkv_w = (const float*)d_in[1];
  const float* qkv_g = (const float*)d_in[2];
  const float* qkv_b = (const float*)d_in[3];
  const float* qkv_m = (const float*)d_in[4];
  const float* qkv_v = (const float*)d_in[5];
  const float* c1_w  = (const float*)d_in[6];
  const float* c1_g  = (const float*)d_in[7];
  const float* c1_b  = (const float*)d_in[8];
  const float* c1_m  = (const float*)d_in[9];
  const float* c1_v  = (const float*)d_in[10];
  const float* c2_w  = (const float*)d_in[11];
  const float* c2_g  = (const float*)d_in[12];
  const float* c2_b  = (const float*)d_in[13];
  const float* c2_m  = (const float*)d_in[14];
  const float* c2_v  = (const float*)d_in[15];
  float* out = (float*)d_out;

  char* wp = (char*)d_ws;
  bf16* Qb = (bf16*)wp;  wp += (size_t)NB * NH * HW * DK * 2;   //  4.7 MB
  bf16* Kb = (bf16*)wp;  wp += (size_t)NB * NH * HW * DK * 2;   //  4.7 MB
  bf16* Vb = (bf16*)wp;  wp += (size_t)NB * NH * DV * HW * 2;   //  9.4 MB
  bf16* Xt = (bf16*)wp;  wp += (size_t)NB * HW * CH * 2;        //  9.4 MB
  bf16* F  = (bf16*)wp;  wp += (size_t)NB * HW * CH * 2;        //  9.4 MB
  bf16* Dw = (bf16*)wp;  wp += (size_t)NB * NH * DV * HW * 2;   //  9.4 MB
  bf16* Wq = (bf16*)wp;  wp += (size_t)QC * CH * 2;
  bf16* W2 = (bf16*)wp;  wp += (size_t)CH * CH * 2;
  float* bq = (float*)wp; wp += QC * 4;
  float* b2 = (float*)wp; wp += CH * 4;
  float* W1 = (float*)wp; wp += CH * 10 * 4;

  wprep<<<dim3(512), 256, 0, stream>>>(qkv_w, qkv_g, qkv_b, qkv_m, qkv_v,
                                       c1_w, c1_g, c1_b, c1_m, c1_v,
                                       c2_w, c2_g, c2_b, c2_m, c2_v,
                                       Wq, bq, W2, b2, W1);
  xprep<<<dim3(36, 4, 8), 256, 0, stream>>>(x, Xt);
  qkv_gemm<<<dim3(36, 8, 8), 256, 0, stream>>>(Xt, Wq, bq, Qb, Kb, Vb);
  dwc<<<dim3(2304), 256, 0, stream>>>(Vb, W1, Dw);
  flash_attn<<<dim3(36, 32), 512, 0, stream>>>(Qb, Kb, Vb, Dw, F);
  c2_gemm<<<dim3(36, 4, 8), 256, 0, stream>>>(F, W2, b2, out);
}